// Round 11
// baseline (1513.249 us; speedup 1.0000x reference)
//
#include <hip/hip_runtime.h>
#include <hip/hip_bf16.h>
#include <math.h>

#define NMSG 16384
#define NNEI 10
#define INF_ 135
#define KPAD 160
#define HID 256
#define DPH 64
#define DEPTH 5

typedef __attribute__((ext_vector_type(8))) short short8b;
typedef __attribute__((ext_vector_type(4))) float f32x4;
typedef __hip_bfloat16 bf16;

__device__ __forceinline__ float sigmoidf_(float x){ return 1.f/(1.f+expf(-x)); }
__device__ __forceinline__ float b2f(unsigned short u){ return __uint_as_float(((unsigned)u)<<16); }
__device__ __forceinline__ float ldb(const bf16* p, size_t off){
    return b2f(*((const unsigned short*)p + off));
}

__device__ __forceinline__ void gload_lds16(const void* g, void* l){
    __builtin_amdgcn_global_load_lds(
        (const __attribute__((address_space(1))) unsigned int*)g,
        (__attribute__((address_space(3))) unsigned int*)l, 16, 0, 0);
}

// software grid barrier: monotonic counter, agent-scope atomics + fences (XCD-safe)
__device__ __forceinline__ void gbar(unsigned* cnt, unsigned target){
    __threadfence();                 // release: make this thread's writes device-visible
    __syncthreads();                 // whole block arrived
    if (threadIdx.x == 0){
        __hip_atomic_fetch_add(cnt, 1u, __ATOMIC_RELEASE, __HIP_MEMORY_SCOPE_AGENT);
        unsigned v;
        do {
            __builtin_amdgcn_s_sleep(2);
            v = __hip_atomic_load(cnt, __ATOMIC_ACQUIRE, __HIP_MEMORY_SCOPE_AGENT);
        } while (v < target);
    }
    __syncthreads();
    __threadfence();                 // acquire: invalidate stale cached lines
}

// ---------------- PRE kernel (standalone dispatch, K=160, BM=128) ----------------
__global__ __launch_bounds__(256) void pre_k(
    const bf16* __restrict__ A1, const bf16* __restrict__ B1, int K,
    const float* __restrict__ b0,
    bf16* __restrict__ Cb0, bf16* __restrict__ Cb1, bf16* __restrict__ Cb2,
    const float* __restrict__ AL, float* __restrict__ SKout)
{
    constexpr int BM=128, BK=32;
    __shared__ __align__(16) unsigned short As1[BM*BK];
    __shared__ __align__(16) unsigned short Bs1[64*BK];
    const int tid = threadIdx.x;
    const int w = tid >> 6, lane = tid & 63;
    const int bm0 = blockIdx.x * BM;
    const int bn0 = blockIdx.y * 64;
    const int rq = lane >> 2, slot = lane & 3;
    const int fr = lane & 15, fs = lane >> 4;
    const int wrow = w * 32;

    f32x4 acc1[2][4] = {};

    for (int k0 = 0; k0 < K; k0 += BK){
        #pragma unroll
        for (int i = 0; i < 2; ++i){
            const int r0 = i*64 + w*16;
            const int r  = r0 + rq;
            const int sw = slot ^ ((r >> 1) & 3);
            gload_lds16(A1 + (size_t)(bm0 + r)*K + k0 + sw*8, As1 + r0*BK);
        }
        {
            const int r0 = w*16;
            const int r  = r0 + rq;
            const int sw = slot ^ ((r >> 1) & 3);
            gload_lds16(B1 + (size_t)(bn0 + r)*K + k0 + sw*8, Bs1 + r0*BK);
        }
        __syncthreads();
        short8b af1[2], bv1[4];
        #pragma unroll
        for (int mi = 0; mi < 2; ++mi){
            const int row = wrow + mi*16 + fr;
            const int sw = fs ^ ((row >> 1) & 3);
            af1[mi] = *(const short8b*)((const char*)As1 + row*64 + sw*16);
        }
        #pragma unroll
        for (int ni = 0; ni < 4; ++ni){
            const int row = ni*16 + fr;
            const int sw = fs ^ ((row >> 1) & 3);
            bv1[ni] = *(const short8b*)((const char*)Bs1 + row*64 + sw*16);
        }
        #pragma unroll
        for (int mi = 0; mi < 2; ++mi)
            #pragma unroll
            for (int ni = 0; ni < 4; ++ni)
                acc1[mi][ni] = __builtin_amdgcn_mfma_f32_16x16x32_bf16(af1[mi], bv1[ni], acc1[mi][ni], 0, 0, 0);
        __syncthreads();
    }

    if (blockIdx.y < 4){
        const int head = blockIdx.y;
        #pragma unroll
        for (int mi = 0; mi < 2; ++mi){
            #pragma unroll
            for (int t = 0; t < 4; ++t){
                float p = 0.f;
                #pragma unroll
                for (int ni = 0; ni < 4; ++ni){
                    const int d = ni*16 + fr;
                    float x = acc1[mi][ni][t] + b0[head*64 + d];
                    float lr = x > 0.f ? x : 0.01f*x;
                    p = fmaf(lr, AL[head*128 + d], p);
                }
                p += __shfl_xor(p,1); p += __shfl_xor(p,2);
                p += __shfl_xor(p,4); p += __shfl_xor(p,8);
                if (fr == 0){
                    const int m = bm0 + wrow + mi*16 + fs*4 + t;
                    SKout[m*4 + head] = p;
                }
            }
        }
    } else {
        const int sel = ((int)blockIdx.y - 4) >> 2;
        bf16* dst = (sel == 0) ? Cb0 : (sel == 1) ? Cb1 : Cb2;
        const int cbase = (((int)blockIdx.y - 4) & 3) * 64;
        #pragma unroll
        for (int mi = 0; mi < 2; ++mi)
            #pragma unroll
            for (int ni = 0; ni < 4; ++ni)
                #pragma unroll
                for (int t = 0; t < 4; ++t){
                    const int m = bm0 + wrow + mi*16 + fs*4 + t;
                    const int c = cbase + ni*16 + fr;
                    dst[(size_t)m*HID + c] = __float2bfloat16(acc1[mi][ni][t]);
                }
    }
}

// ---------------- fused persistent recurrence kernel ----------------
struct FA {
    const int* bgraph;
    const bf16 *Wkb, *Wvb, *Urv, *Wzv, *Wh2b;
    const bf16 *FZb, *FRb, *FHb;
    bf16 *hb, *haggb, *sumhb, *rsb;
    float *S_all, *sq, *sk;
    const float *bk, *bv, *bur2, *bz2, *bh, *alpha, *abias;
    float* out;
    unsigned* cnt;
};

template<bool DA, bool DB>
__device__ __forceinline__ void gemm64(
    const bf16* __restrict__ A1, const bf16* __restrict__ A2,
    const bf16* __restrict__ B1, const bf16* __restrict__ B2,
    int K, int bm0, int bn0,
    unsigned short* LA1, unsigned short* LA2,
    unsigned short* LB1, unsigned short* LB2,
    f32x4 (&acc1)[4], f32x4 (&acc2)[4])
{
    const int tid = threadIdx.x;
    const int w = tid >> 6, lane = tid & 63;
    const int rq = lane >> 2, slot = lane & 3;
    const int fr = lane & 15, fs = lane >> 4;
    for (int k0 = 0; k0 < K; k0 += 32){
        {
            const int r0 = w*16;
            const int r  = r0 + rq;
            const int sw = slot ^ ((r >> 1) & 3);
            gload_lds16(A1 + (size_t)(bm0 + r)*K + k0 + sw*8, LA1 + r0*32);
            if constexpr (DA)
                gload_lds16(A2 + (size_t)(bm0 + r)*K + k0 + sw*8, LA2 + r0*32);
            gload_lds16(B1 + (size_t)(bn0 + r)*K + k0 + sw*8, LB1 + r0*32);
            if constexpr (DB)
                gload_lds16(B2 + (size_t)(bn0 + r)*K + k0 + sw*8, LB2 + r0*32);
        }
        __syncthreads();
        short8b af1, af2, bv1[4], bv2[4];
        {
            const int row = w*16 + fr;
            const int sw = fs ^ ((row >> 1) & 3);
            af1 = *(const short8b*)((const char*)LA1 + row*64 + sw*16);
            if constexpr (DA)
                af2 = *(const short8b*)((const char*)LA2 + row*64 + sw*16);
        }
        #pragma unroll
        for (int ni = 0; ni < 4; ++ni){
            const int row = ni*16 + fr;
            const int sw = fs ^ ((row >> 1) & 3);
            bv1[ni] = *(const short8b*)((const char*)LB1 + row*64 + sw*16);
            if constexpr (DB)
                bv2[ni] = *(const short8b*)((const char*)LB2 + row*64 + sw*16);
        }
        #pragma unroll
        for (int ni = 0; ni < 4; ++ni){
            acc1[ni] = __builtin_amdgcn_mfma_f32_16x16x32_bf16(af1, bv1[ni], acc1[ni], 0, 0, 0);
            if constexpr (DB)
                acc2[ni] = __builtin_amdgcn_mfma_f32_16x16x32_bf16(
                    DA ? af2 : af1, bv2[ni], acc2[ni], 0, 0, 0);
        }
        __syncthreads();
    }
}

__global__ __launch_bounds__(256, 2) void fused_k(FA a){
    __shared__ __align__(16) unsigned short LA1[64*32];
    __shared__ __align__(16) unsigned short LA2[64*32];
    __shared__ __align__(16) unsigned short LB1[64*32];
    __shared__ __align__(16) unsigned short LB2[64*32];
    const int tid = threadIdx.x;
    const int lane = tid & 63;
    const int fr = lane & 15, fs = lane >> 4;
    const int w = tid >> 6;
    unsigned bar = 0;

    for (int step = 0; step < DEPTH; ++step){
        if (step > 0){
            // ---- G1: sk from h @ Wk^T (fused reduction) ----
            for (int t = blockIdx.x; t < 1024; t += gridDim.x){
                const int bm0 = (t & 255) * 64, head = t >> 8;
                f32x4 acc1[4] = {}; f32x4 acc2[4];
                gemm64<false,false>(a.hb, nullptr, a.Wkb, nullptr, HID,
                                    bm0, head*64, LA1, LA2, LB1, LB2, acc1, acc2);
                #pragma unroll
                for (int tt = 0; tt < 4; ++tt){
                    float p = 0.f;
                    #pragma unroll
                    for (int ni = 0; ni < 4; ++ni){
                        const int d = ni*16 + fr;
                        float x = acc1[ni][tt] + a.bk[head*64 + d];
                        float lr = x > 0.f ? x : 0.01f*x;
                        p = fmaf(lr, a.alpha[head*128 + 64 + d], p);
                    }
                    p += __shfl_xor(p,1); p += __shfl_xor(p,2);
                    p += __shfl_xor(p,4); p += __shfl_xor(p,8);
                    if (fr == 0){
                        const int m = bm0 + w*16 + fs*4 + tt;
                        a.sk[m*4 + head] = p;
                    }
                }
            }
            bar += gridDim.x; gbar(a.cnt, bar);
            // ---- attention: h_agg = softmax-weighted gather of h ----
            const float* S = a.S_all + (size_t)step*NMSG;
            for (int t = blockIdx.x; t < NMSG/4; t += gridDim.x){
                const int n = t*4 + (tid >> 6);
                const int head4 = lane >> 4;
                const float ab  = a.abias[head4];
                const float sqv = a.sq[n*4 + head4];
                int gidx[NNEI];
                #pragma unroll
                for (int j = 0; j < NNEI; ++j) gidx[j] = a.bgraph[n*NNEI + j];
                float sc[NNEI];
                float mx = -1e30f;
                #pragma unroll
                for (int j = 0; j < NNEI; ++j){
                    float s = sqv + a.sk[gidx[j]*4 + head4] + ab;
                    if (S[gidx[j]] == 0.f) s = -1e18f;
                    sc[j] = s;
                    mx = fmaxf(mx, s);
                }
                float den = 0.f;
                #pragma unroll
                for (int j = 0; j < NNEI; ++j){ sc[j] = expf(sc[j] - mx); den += sc[j]; }
                const float inv = 1.f/den;
                float a0=0.f, a1=0.f, a2=0.f, a3=0.f;
                #pragma unroll
                for (int j = 0; j < NNEI; ++j){
                    const float wj = sc[j]*inv;
                    const ushort4 vv = *reinterpret_cast<const ushort4*>(
                        (const unsigned short*)a.hb + (size_t)gidx[j]*HID + lane*4);
                    a0 = fmaf(wj, b2f(vv.x), a0);
                    a1 = fmaf(wj, b2f(vv.y), a1);
                    a2 = fmaf(wj, b2f(vv.z), a2);
                    a3 = fmaf(wj, b2f(vv.w), a3);
                }
                ushort4 ob;
                { bf16 t0=__float2bfloat16(a0); ob.x=*(unsigned short*)&t0; }
                { bf16 t1=__float2bfloat16(a1); ob.y=*(unsigned short*)&t1; }
                { bf16 t2=__float2bfloat16(a2); ob.z=*(unsigned short*)&t2; }
                { bf16 t3=__float2bfloat16(a3); ob.w=*(unsigned short*)&t3; }
                *reinterpret_cast<ushort4*>((unsigned short*)a.haggb + (size_t)n*HID + lane*4) = ob;
            }
            bar += gridDim.x; gbar(a.cnt, bar);
        }
        // ---- G2: {sumh = hagg@Wv^T + bv ; rs = sigmoid(hagg@Urv^T + Fr + bur2) * sumh} ----
        for (int t = blockIdx.x; t < 1024; t += gridDim.x){
            const int bm0 = (t & 255) * 64, bn0 = (t >> 8) * 64;
            f32x4 acc1[4] = {}; f32x4 acc2[4] = {};
            gemm64<false,true>(a.haggb, nullptr, a.Wvb, a.Urv, HID,
                               bm0, bn0, LA1, LA2, LB1, LB2, acc1, acc2);
            #pragma unroll
            for (int ni = 0; ni < 4; ++ni)
                #pragma unroll
                for (int tt = 0; tt < 4; ++tt){
                    const int m = bm0 + w*16 + fs*4 + tt;
                    const int c = bn0 + ni*16 + fr;
                    const size_t off = (size_t)m*HID + c;
                    const float sumh = acc1[ni][tt] + a.bv[c];
                    const float r = sigmoidf_(acc2[ni][tt] + ldb(a.FRb, off) + a.bur2[c]);
                    a.sumhb[off] = __float2bfloat16(sumh);
                    a.rsb[off]   = __float2bfloat16(r * sumh);
                }
        }
        bar += gridDim.x; gbar(a.cnt, bar);
        // ---- G3: {z = sigmoid(hagg@Wzv^T + Fz + bz2) ; h = (1-z)sumh + z tanh(rs@Wh2^T + Fh + bh)} ----
        const bool last = (step == DEPTH-1);
        float* Snext = last ? nullptr : (a.S_all + (size_t)(step+1)*NMSG);
        for (int t = blockIdx.x; t < 1024; t += gridDim.x){
            const int bm0 = (t & 255) * 64, bn0 = (t >> 8) * 64;
            f32x4 acc1[4] = {}; f32x4 acc2[4] = {};
            gemm64<true,true>(a.rsb, a.haggb, a.Wh2b, a.Wzv, HID,
                              bm0, bn0, LA1, LA2, LB1, LB2, acc1, acc2);
            #pragma unroll
            for (int tt = 0; tt < 4; ++tt){
                const int m = bm0 + w*16 + fs*4 + tt;
                float psum = 0.f;
                #pragma unroll
                for (int ni = 0; ni < 4; ++ni){
                    const int c = bn0 + ni*16 + fr;
                    const size_t off = (size_t)m*HID + c;
                    const float ph = tanhf(acc1[ni][tt] + ldb(a.FHb, off) + a.bh[c]);
                    const float z  = sigmoidf_(acc2[ni][tt] + ldb(a.FZb, off) + a.bz2[c]);
                    const float sh = ldb(a.sumhb, off);
                    float hn = (1.f - z)*sh + z*ph;
                    if (m == 0) hn = 0.f;
                    if (last) a.out[off] = hn;
                    else      a.hb[off] = __float2bfloat16(hn);
                    psum += hn;
                }
                if (Snext){
                    psum += __shfl_xor(psum,1); psum += __shfl_xor(psum,2);
                    psum += __shfl_xor(psum,4); psum += __shfl_xor(psum,8);
                    if (fr == 0) atomicAdd(&Snext[m], psum);
                }
            }
        }
        if (!last){ bar += gridDim.x; gbar(a.cnt, bar); }
    }
}

// ---------------- host-side prep kernels ----------------
struct ConvSegs {
    const float* src[8];
    bf16* dst[8];
    int srcld[8], col0[8], ncols[8], dstld[8];
    int start[8];
};
__global__ __launch_bounds__(256) void convall_k(ConvSegs cs, int total){
    int i = blockIdx.x*256 + threadIdx.x;
    if (i >= total) return;
    int s = 0;
    #pragma unroll
    for (int j = 1; j < 8; ++j) if (i >= cs.start[j]) s = j;
    const int li = i - cs.start[s];
    const int ld = cs.dstld[s];
    const int r = li / ld, c = li - r*ld;
    float v = (c < cs.ncols[s]) ? cs.src[s][(size_t)r*cs.srcld[s] + cs.col0[s] + c] : 0.f;
    cs.dst[s][li] = __float2bfloat16(v);
}

__global__ __launch_bounds__(256) void wcomb_k(
    const float* __restrict__ Ur, const float* __restrict__ Wz,
    const float* __restrict__ Wv, const float* __restrict__ bv,
    const float* __restrict__ bur, const float* __restrict__ bz,
    bf16* __restrict__ Urv, bf16* __restrict__ Wzv,
    float* __restrict__ bur2, float* __restrict__ bz2)
{
    const int i = blockIdx.x, j = threadIdx.x;
    const bool zp = (i >= 256);
    const int r = zp ? i - 256 : i;
    const float* Arow = zp ? (Wz + (size_t)r*(INF_+HID) + INF_) : (Ur + (size_t)r*HID);
    float acc = 0.f;
    for (int q = 0; q < HID; ++q)
        acc = fmaf(Arow[q], Wv[(size_t)q*HID + j], acc);
    (zp ? Wzv : Urv)[(size_t)r*HID + j] = __float2bfloat16(acc);
    float part = Arow[j] * bv[j];
    part += __shfl_xor(part,1);  part += __shfl_xor(part,2);  part += __shfl_xor(part,4);
    part += __shfl_xor(part,8);  part += __shfl_xor(part,16); part += __shfl_xor(part,32);
    __shared__ float red[4];
    if ((j & 63) == 0) red[j >> 6] = part;
    __syncthreads();
    if (j == 0){
        float s = red[0] + red[1] + red[2] + red[3];
        if (zp) bz2[r] = bz[r] + s; else bur2[r] = bur[r] + s;
    }
}

extern "C" void kernel_launch(void* const* d_in, const int* in_sizes, int n_in,
                              void* d_out, int out_size, void* d_ws, size_t ws_size,
                              hipStream_t stream) {
    const float* fmess = (const float*)d_in[0];
    const int*   bgraph= (const int*  )d_in[1];
    const float* Wq    = (const float*)d_in[2];
    const float* bq    = (const float*)d_in[3];
    const float* Wk    = (const float*)d_in[4];
    const float* bk    = (const float*)d_in[5];
    const float* Wv    = (const float*)d_in[6];
    const float* bv    = (const float*)d_in[7];
    const float* alpha = (const float*)d_in[8];
    const float* abias = (const float*)d_in[9];
    const float* Wz    = (const float*)d_in[10];
    const float* bz    = (const float*)d_in[11];
    const float* Wr    = (const float*)d_in[12];
    const float* Ur    = (const float*)d_in[13];
    const float* bur   = (const float*)d_in[14];
    const float* Wh    = (const float*)d_in[15];
    const float* bh    = (const float*)d_in[16];
    float* out = (float*)d_out;

    const size_t NH = (size_t)NMSG*HID;
    char* p = (char*)d_ws;
    auto alloc = [&](size_t bytes)->char*{ char* r = p; p += (bytes + 255) & ~(size_t)255; return r; };
    bf16* fmessb = (bf16*)alloc((size_t)NMSG*KPAD*2);
    bf16* Wcat   = (bf16*)alloc((size_t)1024*KPAD*2);
    bf16* Wkb    = (bf16*)alloc((size_t)256*HID*2);
    bf16* Wvb    = (bf16*)alloc((size_t)256*HID*2);
    bf16* Wh2b   = (bf16*)alloc((size_t)256*HID*2);
    bf16* Urv    = (bf16*)alloc((size_t)256*HID*2);
    bf16* Wzv    = (bf16*)alloc((size_t)256*HID*2);
    float* bur2  = (float*)alloc(256*4);
    float* bz2   = (float*)alloc(256*4);
    bf16* FZb    = (bf16*)alloc(NH*2);
    bf16* FRb    = (bf16*)alloc(NH*2);
    bf16* FHb    = (bf16*)alloc(NH*2);
    bf16* sumhb  = (bf16*)alloc(NH*2);
    bf16* rsb    = (bf16*)alloc(NH*2);
    // contiguous zero region: cnt | hb | haggb | S_all[5]
    char* zreg   = alloc(256 + NH*2 + NH*2 + 5*(size_t)NMSG*4);
    unsigned* cnt = (unsigned*)zreg;
    bf16*  hb    = (bf16*)(zreg + 256);
    bf16*  haggb = (bf16*)(zreg + 256 + NH*2);
    float* S_all = (float*)(zreg + 256 + NH*2 + NH*2);
    const size_t zbytes = 256 + NH*2 + NH*2 + 5*(size_t)NMSG*4;
    float* sq    = (float*)alloc((size_t)NMSG*4*4);
    float* sk    = (float*)alloc((size_t)NMSG*4*4);

    const dim3 gb(256);

    // ---- conversions (8 segments, one launch) ----
    {
        ConvSegs cs;
        const size_t WQK = (size_t)256*KPAD;
        const float* srcs[8] = {fmess, Wq, Wz, Wr, Wh, Wk, Wv, Wh};
        bf16* dsts[8] = {fmessb, Wcat, Wcat+WQK, Wcat+2*WQK, Wcat+3*WQK, Wkb, Wvb, Wh2b};
        int srclds[8] = {INF_, INF_, INF_+HID, INF_, INF_+HID, HID, HID, INF_+HID};
        int col0s[8]  = {0,0,0,0,0, 0,0,INF_};
        int ncolss[8] = {INF_,INF_,INF_,INF_,INF_, HID,HID,HID};
        int dstlds[8] = {KPAD,KPAD,KPAD,KPAD,KPAD, HID,HID,HID};
        int sizes[8]  = {NMSG*KPAD, 256*KPAD,256*KPAD,256*KPAD,256*KPAD,
                         256*HID,256*HID,256*HID};
        int st = 0;
        for (int j = 0; j < 8; ++j){
            cs.src[j]=srcs[j]; cs.dst[j]=dsts[j]; cs.srcld[j]=srclds[j];
            cs.col0[j]=col0s[j]; cs.ncols[j]=ncolss[j]; cs.dstld[j]=dstlds[j];
            cs.start[j]=st; st += sizes[j];
        }
        convall_k<<<(st+255)/256, gb, 0, stream>>>(cs, st);
    }
    wcomb_k<<<512, gb, 0, stream>>>(Ur, Wz, Wv, bv, bur, bz, Urv, Wzv, bur2, bz2);
    hipMemsetAsync(zreg, 0, zbytes, stream);

    // ---- precompute: [sq | Fz | Fr | Fh] = fmess_bf16 @ Wcat^T (K=160) ----
    pre_k<<<dim3(NMSG/128, 16), gb, 0, stream>>>(fmessb, Wcat, KPAD,
        bq, FZb, FRb, FHb, alpha, sq);

    // ---- fused persistent recurrence (normal launch + software grid barrier) ----
    FA fa;
    fa.bgraph = bgraph;
    fa.Wkb = Wkb; fa.Wvb = Wvb; fa.Urv = Urv; fa.Wzv = Wzv; fa.Wh2b = Wh2b;
    fa.FZb = FZb; fa.FRb = FRb; fa.FHb = FHb;
    fa.hb = hb; fa.haggb = haggb; fa.sumhb = sumhb; fa.rsb = rsb;
    fa.S_all = S_all; fa.sq = sq; fa.sk = sk;
    fa.bk = bk; fa.bv = bv; fa.bur2 = bur2; fa.bz2 = bz2; fa.bh = bh;
    fa.alpha = alpha; fa.abias = abias;
    fa.out = out;
    fa.cnt = cnt;

    int occ = 0;
    if (hipOccupancyMaxActiveBlocksPerMultiprocessor(&occ, (const void*)fused_k, 256, 0)
            != hipSuccess || occ < 1)
        occ = 1;
    int grid = occ * 256;            // 256 CUs on MI355X
    if (grid > 512) grid = 512;
    fused_k<<<dim3(grid), gb, 0, stream>>>(fa);
}